// Round 1
// baseline (838.221 us; speedup 1.0000x reference)
//
#include <hip/hip_runtime.h>

// ---------------------------------------------------------------------------
// GCN 3-layer forward on MI355X.
//   per layer: y = relu( A_hat @ (x @ W) + b )
// A_hat built once per call as CSR-by-destination with GCN symmetric norm.
// One wave (64 lanes) per node; lane == feature (D == 64 == wavefront).
// ---------------------------------------------------------------------------

#define THREADS 256

__global__ __launch_bounds__(THREADS)
void hist_kernel(const int* __restrict__ dst, int* __restrict__ cnt, int E) {
    int stride = gridDim.x * blockDim.x;
    for (int e = blockIdx.x * blockDim.x + threadIdx.x; e < E; e += stride)
        atomicAdd(&cnt[dst[e]], 1);
}

// block scans 1024 elements (256 threads x 4); writes exclusive prefix + block sum
__global__ __launch_bounds__(THREADS)
void scan1_kernel(const int* __restrict__ cnt, int* __restrict__ out,
                  int* __restrict__ bsums, int n) {
    __shared__ int tmp[THREADS];
    int tid  = threadIdx.x;
    int base = blockIdx.x * 1024 + tid * 4;
    int v0 = (base + 0 < n) ? cnt[base + 0] : 0;
    int v1 = (base + 1 < n) ? cnt[base + 1] : 0;
    int v2 = (base + 2 < n) ? cnt[base + 2] : 0;
    int v3 = (base + 3 < n) ? cnt[base + 3] : 0;
    int tsum = v0 + v1 + v2 + v3;
    tmp[tid] = tsum;
    __syncthreads();
    for (int off = 1; off < THREADS; off <<= 1) {
        int t = (tid >= off) ? tmp[tid - off] : 0;
        __syncthreads();
        tmp[tid] += t;
        __syncthreads();
    }
    int excl = tmp[tid] - tsum;  // exclusive within block
    if (base + 0 < n) out[base + 0] = excl; excl += v0;
    if (base + 1 < n) out[base + 1] = excl; excl += v1;
    if (base + 2 < n) out[base + 2] = excl; excl += v2;
    if (base + 3 < n) out[base + 3] = excl;
    if (tid == THREADS - 1) bsums[blockIdx.x] = tmp[THREADS - 1];
}

__global__ void scan2_kernel(int* bsums, int nb) {
    if (blockIdx.x == 0 && threadIdx.x == 0) {
        int acc = 0;
        for (int i = 0; i < nb; ++i) { int t = bsums[i]; bsums[i] = acc; acc += t; }
    }
}

__global__ __launch_bounds__(THREADS)
void scan3_kernel(int* __restrict__ rowptr, const int* __restrict__ bsums,
                  int n, int total) {
    int stride = gridDim.x * blockDim.x;
    int gid = blockIdx.x * blockDim.x + threadIdx.x;
    for (int i = gid; i < n; i += stride) rowptr[i] += bsums[i >> 10];
    if (gid == 0) rowptr[n] = total;
}

__global__ __launch_bounds__(THREADS)
void dinv_kernel(const int* __restrict__ cnt, float* __restrict__ dinv, int n) {
    int stride = gridDim.x * blockDim.x;
    for (int i = blockIdx.x * blockDim.x + threadIdx.x; i < n; i += stride)
        dinv[i] = rsqrtf((float)(cnt[i] + 1));  // +1 self-loop; always > 0
}

__global__ __launch_bounds__(THREADS)
void fill_kernel(const int* __restrict__ src, const int* __restrict__ dst,
                 const int* __restrict__ rowptr, int* __restrict__ cursor,
                 int* __restrict__ csrc, float* __restrict__ cnorm,
                 const float* __restrict__ dinv, int E) {
    int stride = gridDim.x * blockDim.x;
    for (int e = blockIdx.x * blockDim.x + threadIdx.x; e < E; e += stride) {
        int s = src[e], d = dst[e];
        int pos = atomicAdd(&cursor[d], 1);
        int idx = rowptr[d] + pos;
        csrc[idx]  = s;
        cnorm[idx] = dinv[s] * dinv[d];
    }
}

// H[row,:] = X[row,:] @ W   (64x64). One wave per row; lane = out feature.
// Row-local => safe to call with H == X (all loads of a row complete before
// the single dependent store; waves own disjoint rows).
__global__ __launch_bounds__(THREADS)
void gemm64_kernel(const float* X, float* H, const float* __restrict__ W, int n) {
    __shared__ float Wl[64 * 64];
    for (int i = threadIdx.x; i < 64 * 64; i += blockDim.x) Wl[i] = W[i];
    __syncthreads();
    int lane = threadIdx.x & 63;
    int wave = (blockIdx.x * blockDim.x + threadIdx.x) >> 6;
    int nw   = (gridDim.x * blockDim.x) >> 6;
    for (int row = wave; row < n; row += nw) {
        const float4* xr = (const float4*)(X + (size_t)row * 64);
        float acc = 0.f;
#pragma unroll
        for (int k4 = 0; k4 < 16; ++k4) {
            float4 xv = xr[k4];  // wave-uniform broadcast load
            acc = fmaf(xv.x, Wl[(4 * k4 + 0) * 64 + lane], acc);
            acc = fmaf(xv.y, Wl[(4 * k4 + 1) * 64 + lane], acc);
            acc = fmaf(xv.z, Wl[(4 * k4 + 2) * 64 + lane], acc);
            acc = fmaf(xv.w, Wl[(4 * k4 + 3) * 64 + lane], acc);
        }
        H[(size_t)row * 64 + lane] = acc;
    }
}

// y[i,:] = relu( dinv[i]^2 * H[i,:] + sum_{e in CSR row i} cnorm[e]*H[csrc[e],:] + b )
__global__ __launch_bounds__(THREADS)
void agg_kernel(const float* __restrict__ H, float* __restrict__ Y,
                const int* __restrict__ rowptr, const int* __restrict__ csrc,
                const float* __restrict__ cnorm, const float* __restrict__ dinv,
                const float* __restrict__ bias, int n) {
    int lane = threadIdx.x & 63;
    int wave = (blockIdx.x * blockDim.x + threadIdx.x) >> 6;
    int nw   = (gridDim.x * blockDim.x) >> 6;
    float b = bias[lane];
    for (int i = wave; i < n; i += nw) {
        float di  = dinv[i];
        float acc = H[(size_t)i * 64 + lane] * (di * di);  // self-loop
        int k0 = rowptr[i], k1 = rowptr[i + 1];
        for (int k = k0; k < k1; ++k) {
            int   s  = csrc[k];   // wave-uniform broadcast
            float wv = cnorm[k];
            acc = fmaf(H[(size_t)s * 64 + lane], wv, acc);  // 256B coalesced row
        }
        float o = acc + b;
        Y[(size_t)i * 64 + lane] = o > 0.f ? o : 0.f;
    }
}

extern "C" void kernel_launch(void* const* d_in, const int* in_sizes, int n_in,
                              void* d_out, int out_size, void* d_ws, size_t ws_size,
                              hipStream_t stream) {
    const float* x  = (const float*)d_in[0];
    const int*   ei = (const int*)d_in[1];
    const float* W0 = (const float*)d_in[2];
    const float* b0 = (const float*)d_in[3];
    const float* W1 = (const float*)d_in[4];
    const float* b1 = (const float*)d_in[5];
    const float* W2 = (const float*)d_in[6];
    const float* b2 = (const float*)d_in[7];

    const int N = in_sizes[0] / 64;
    const int E = in_sizes[1] / 2;
    const int* src = ei;       // edge_index[0]
    const int* dst = ei + E;   // edge_index[1]

    // ---- workspace layout (256B-aligned slices) ----
    char*  ws  = (char*)d_ws;
    size_t off = 0;
    auto alloc = [&](size_t bytes) -> void* {
        void* p = ws + off;
        off += (bytes + 255) & ~(size_t)255;
        return p;
    };
    int*   cnt    = (int*)  alloc((size_t)N * 4);
    int*   cursor = (int*)  alloc((size_t)N * 4);
    int*   rowptr = (int*)  alloc((size_t)(N + 1) * 4);
    int*   bsums  = (int*)  alloc(1024);
    float* dinv   = (float*)alloc((size_t)N * 4);
    int*   csrc   = (int*)  alloc((size_t)E * 4);
    float* cnorm  = (float*)alloc((size_t)E * 4);
    float* actA   = (float*)alloc((size_t)N * 64 * 4);
    float* outb   = (float*)d_out;   // doubles as second activation buffer

    hipMemsetAsync(cnt,    0, (size_t)N * 4, stream);
    hipMemsetAsync(cursor, 0, (size_t)N * 4, stream);

    const int egrid = 2048;
    const int ngrid = 2048;
    const int nb = (N + 1023) / 1024;

    hist_kernel <<<egrid, THREADS, 0, stream>>>(dst, cnt, E);
    scan1_kernel<<<nb,    THREADS, 0, stream>>>(cnt, rowptr, bsums, N);
    scan2_kernel<<<1, 64, 0, stream>>>(bsums, nb);
    scan3_kernel<<<512,   THREADS, 0, stream>>>(rowptr, bsums, N, E);
    dinv_kernel <<<512,   THREADS, 0, stream>>>(cnt, dinv, N);
    fill_kernel <<<egrid, THREADS, 0, stream>>>(src, dst, rowptr, cursor,
                                                csrc, cnorm, dinv, E);

    // layer 0: x -> actA (transform) -> outb (aggregate)
    gemm64_kernel<<<ngrid, THREADS, 0, stream>>>(x, actA, W0, N);
    agg_kernel  <<<ngrid, THREADS, 0, stream>>>(actA, outb, rowptr, csrc, cnorm, dinv, b0, N);
    // layer 1: outb -> outb (in-place transform) -> actA
    gemm64_kernel<<<ngrid, THREADS, 0, stream>>>(outb, outb, W1, N);
    agg_kernel  <<<ngrid, THREADS, 0, stream>>>(outb, actA, rowptr, csrc, cnorm, dinv, b1, N);
    // layer 2: actA -> actA (in-place transform) -> d_out
    gemm64_kernel<<<ngrid, THREADS, 0, stream>>>(actA, actA, W2, N);
    agg_kernel  <<<ngrid, THREADS, 0, stream>>>(actA, outb, rowptr, csrc, cnorm, dinv, b2, N);
}

// Round 2
// 444.329 us; speedup vs baseline: 1.8865x; 1.8865x over previous
//
#include <hip/hip_runtime.h>

// ---------------------------------------------------------------------------
// GCN 3-layer forward on MI355X.
//   per layer: y = relu( A_hat @ (x @ W) + b )
// CSR-by-destination built once per call. Aggregation: one wave per node,
// 4 lane-groups x 16 lanes x float4 => 4 edge rows gathered per VMEM instr.
// ---------------------------------------------------------------------------

#define THREADS 256

__global__ __launch_bounds__(THREADS)
void hist_kernel(const int* __restrict__ dst, int* __restrict__ cnt, int E) {
    int stride = gridDim.x * blockDim.x;
    for (int e = blockIdx.x * blockDim.x + threadIdx.x; e < E; e += stride)
        atomicAdd(&cnt[dst[e]], 1);
}

// block scans 1024 elements (256 threads x 4); writes exclusive prefix + block sum
__global__ __launch_bounds__(THREADS)
void scan1_kernel(const int* __restrict__ cnt, int* __restrict__ out,
                  int* __restrict__ bsums, int n) {
    __shared__ int tmp[THREADS];
    int tid  = threadIdx.x;
    int base = blockIdx.x * 1024 + tid * 4;
    int v0 = (base + 0 < n) ? cnt[base + 0] : 0;
    int v1 = (base + 1 < n) ? cnt[base + 1] : 0;
    int v2 = (base + 2 < n) ? cnt[base + 2] : 0;
    int v3 = (base + 3 < n) ? cnt[base + 3] : 0;
    int tsum = v0 + v1 + v2 + v3;
    tmp[tid] = tsum;
    __syncthreads();
    for (int off = 1; off < THREADS; off <<= 1) {
        int t = (tid >= off) ? tmp[tid - off] : 0;
        __syncthreads();
        tmp[tid] += t;
        __syncthreads();
    }
    int excl = tmp[tid] - tsum;  // exclusive within block
    if (base + 0 < n) out[base + 0] = excl; excl += v0;
    if (base + 1 < n) out[base + 1] = excl; excl += v1;
    if (base + 2 < n) out[base + 2] = excl; excl += v2;
    if (base + 3 < n) out[base + 3] = excl;
    if (tid == THREADS - 1) bsums[blockIdx.x] = tmp[THREADS - 1];
}

// exclusive scan of block sums (nb <= 256 fast path; serial fallback)
__global__ __launch_bounds__(THREADS)
void scan2_kernel(int* bsums, int nb) {
    __shared__ int tmp[THREADS];
    int tid = threadIdx.x;
    if (nb <= THREADS) {
        int v = (tid < nb) ? bsums[tid] : 0;
        tmp[tid] = v;
        __syncthreads();
        for (int off = 1; off < THREADS; off <<= 1) {
            int t = (tid >= off) ? tmp[tid - off] : 0;
            __syncthreads();
            tmp[tid] += t;
            __syncthreads();
        }
        if (tid < nb) bsums[tid] = tmp[tid] - v;
    } else if (tid == 0) {
        int acc = 0;
        for (int i = 0; i < nb; ++i) { int t = bsums[i]; bsums[i] = acc; acc += t; }
    }
}

__global__ __launch_bounds__(THREADS)
void scan3_kernel(int* __restrict__ rowptr, const int* __restrict__ bsums,
                  int n, int total) {
    int stride = gridDim.x * blockDim.x;
    int gid = blockIdx.x * blockDim.x + threadIdx.x;
    for (int i = gid; i < n; i += stride) rowptr[i] += bsums[i >> 10];
    if (gid == 0) rowptr[n] = total;
}

__global__ __launch_bounds__(THREADS)
void dinv_kernel(const int* __restrict__ cnt, float* __restrict__ dinv, int n) {
    int stride = gridDim.x * blockDim.x;
    for (int i = blockIdx.x * blockDim.x + threadIdx.x; i < n; i += stride)
        dinv[i] = rsqrtf((float)(cnt[i] + 1));  // +1 self-loop; always > 0
}

// fill interleaved {src, norm} pairs per CSR slot
__global__ __launch_bounds__(THREADS)
void fill_kernel(const int* __restrict__ src, const int* __restrict__ dst,
                 const int* __restrict__ rowptr, int* __restrict__ cursor,
                 int2* __restrict__ cpair, const float* __restrict__ dinv, int E) {
    int stride = gridDim.x * blockDim.x;
    for (int e = blockIdx.x * blockDim.x + threadIdx.x; e < E; e += stride) {
        int s = src[e], d = dst[e];
        int pos = atomicAdd(&cursor[d], 1);
        int idx = rowptr[d] + pos;
        float w = dinv[s] * dinv[d];
        cpair[idx] = make_int2(s, __float_as_int(w));
    }
}

// H[row,:] = X[row,:] @ W   (64x64). One wave per row; lane = out feature.
// W column held in 64 registers per lane; X row loads are wave-uniform.
// Row-local => safe in-place (H == X).
__global__ __launch_bounds__(THREADS)
void gemm64_kernel(const float* __restrict__ X, float* __restrict__ H,
                   const float* __restrict__ W, int n) {
    int lane = threadIdx.x & 63;
    float w[64];
#pragma unroll
    for (int k = 0; k < 64; ++k) w[k] = W[k * 64 + lane];  // coalesced, once
    int wave = (blockIdx.x * blockDim.x + threadIdx.x) >> 6;
    int nw   = (gridDim.x * blockDim.x) >> 6;
    for (int row = wave; row < n; row += nw) {
        int ru = __builtin_amdgcn_readfirstlane(row);  // provably uniform
        const float4* xr = (const float4*)(X + (size_t)ru * 64);
        float acc = 0.f;
#pragma unroll
        for (int k4 = 0; k4 < 16; ++k4) {
            float4 xv = xr[k4];  // uniform broadcast load
            acc = fmaf(xv.x, w[4 * k4 + 0], acc);
            acc = fmaf(xv.y, w[4 * k4 + 1], acc);
            acc = fmaf(xv.z, w[4 * k4 + 2], acc);
            acc = fmaf(xv.w, w[4 * k4 + 3], acc);
        }
        H[(size_t)ru * 64 + lane] = acc;
    }
}

// y[i,:] = relu( dinv[i]^2*H[i,:] + sum_e norm[e]*H[src[e],:] + b )
// Wave layout: 4 groups x 16 lanes; group g processes edge (base+g);
// lane covers features (lane&15)*4 .. +3 as float4.
__global__ __launch_bounds__(THREADS)
void agg_kernel(const float* __restrict__ H, float* __restrict__ Y,
                const int* __restrict__ rowptr, const int2* __restrict__ cpair,
                const float* __restrict__ dinv, const float* __restrict__ bias,
                int n) {
    int lane = threadIdx.x & 63;
    int grp  = lane >> 4;          // 0..3
    int fl   = (lane & 15) * 4;    // feature offset of this lane's float4
    int wave = (blockIdx.x * blockDim.x + threadIdx.x) >> 6;
    int nw   = (gridDim.x * blockDim.x) >> 6;
    float4 bv = *(const float4*)(bias + fl);
    for (int i = wave; i < n; i += nw) {
        int k0 = rowptr[i], k1 = rowptr[i + 1];
        float di = dinv[i];
        float4 acc = make_float4(0.f, 0.f, 0.f, 0.f);
        if (grp == 0) {  // self-loop term
            float4 hv = *(const float4*)(H + (size_t)i * 64 + fl);
            float sw = di * di;
            acc.x = hv.x * sw; acc.y = hv.y * sw;
            acc.z = hv.z * sw; acc.w = hv.w * sw;
        }
        if (k0 < k1) {
            // software-pipelined: prefetch next {src,norm} while gathering
            int kk = k0 + grp;
            int kc = (kk < k1) ? kk : k0;
            int2 p = cpair[kc];
            int   s  = p.x;
            float wv = (kk < k1) ? __int_as_float(p.y) : 0.f;
            for (int base = k0; base < k1; base += 4) {
                const float4 hv = *(const float4*)(H + (size_t)s * 64 + fl);
                int kk2 = kk + 4;
                int kc2 = (kk2 < k1) ? kk2 : k0;
                int2 p2 = cpair[kc2];            // independent of hv
                float wv2 = (kk2 < k1) ? __int_as_float(p2.y) : 0.f;
                acc.x = fmaf(hv.x, wv, acc.x);
                acc.y = fmaf(hv.y, wv, acc.y);
                acc.z = fmaf(hv.z, wv, acc.z);
                acc.w = fmaf(hv.w, wv, acc.w);
                s = p2.x; wv = wv2; kk = kk2;
            }
        }
        // reduce partial sums across the 4 groups (lanes stride 16)
        acc.x += __shfl_xor(acc.x, 16); acc.x += __shfl_xor(acc.x, 32);
        acc.y += __shfl_xor(acc.y, 16); acc.y += __shfl_xor(acc.y, 32);
        acc.z += __shfl_xor(acc.z, 16); acc.z += __shfl_xor(acc.z, 32);
        acc.w += __shfl_xor(acc.w, 16); acc.w += __shfl_xor(acc.w, 32);
        if (grp == 0) {
            float4 o;
            o.x = fmaxf(acc.x + bv.x, 0.f);
            o.y = fmaxf(acc.y + bv.y, 0.f);
            o.z = fmaxf(acc.z + bv.z, 0.f);
            o.w = fmaxf(acc.w + bv.w, 0.f);
            *(float4*)(Y + (size_t)i * 64 + fl) = o;
        }
    }
}

extern "C" void kernel_launch(void* const* d_in, const int* in_sizes, int n_in,
                              void* d_out, int out_size, void* d_ws, size_t ws_size,
                              hipStream_t stream) {
    const float* x  = (const float*)d_in[0];
    const int*   ei = (const int*)d_in[1];
    const float* W0 = (const float*)d_in[2];
    const float* b0 = (const float*)d_in[3];
    const float* W1 = (const float*)d_in[4];
    const float* b1 = (const float*)d_in[5];
    const float* W2 = (const float*)d_in[6];
    const float* b2 = (const float*)d_in[7];

    const int N = in_sizes[0] / 64;
    const int E = in_sizes[1] / 2;
    const int* src = ei;       // edge_index[0]
    const int* dst = ei + E;   // edge_index[1]

    // ---- workspace layout (256B-aligned slices) ----
    char*  ws  = (char*)d_ws;
    size_t off = 0;
    auto alloc = [&](size_t bytes) -> void* {
        void* p = ws + off;
        off += (bytes + 255) & ~(size_t)255;
        return p;
    };
    int*   cnt    = (int*)  alloc((size_t)N * 4);
    int*   cursor = (int*)  alloc((size_t)N * 4);
    int*   rowptr = (int*)  alloc((size_t)(N + 1) * 4);
    int*   bsums  = (int*)  alloc(4096);
    float* dinv   = (float*)alloc((size_t)N * 4);
    int2*  cpair  = (int2*) alloc((size_t)E * 8);
    float* actA   = (float*)alloc((size_t)N * 64 * 4);
    float* outb   = (float*)d_out;   // doubles as second activation buffer

    hipMemsetAsync(cnt,    0, (size_t)N * 4, stream);
    hipMemsetAsync(cursor, 0, (size_t)N * 4, stream);

    const int egrid = 2048;
    const int ngrid = 2048;   // agg: 8 blocks/CU
    const int ggrid = 1280;   // gemm: 5 blocks/CU (high VGPR)
    const int nb = (N + 1023) / 1024;

    hist_kernel <<<egrid, THREADS, 0, stream>>>(dst, cnt, E);
    scan1_kernel<<<nb,    THREADS, 0, stream>>>(cnt, rowptr, bsums, N);
    scan2_kernel<<<1,     THREADS, 0, stream>>>(bsums, nb);
    scan3_kernel<<<512,   THREADS, 0, stream>>>(rowptr, bsums, N, E);
    dinv_kernel <<<512,   THREADS, 0, stream>>>(cnt, dinv, N);
    fill_kernel <<<egrid, THREADS, 0, stream>>>(src, dst, rowptr, cursor,
                                                cpair, dinv, E);

    // layer 0: x -> actA (transform) -> outb (aggregate)
    gemm64_kernel<<<ggrid, THREADS, 0, stream>>>(x, actA, W0, N);
    agg_kernel  <<<ngrid, THREADS, 0, stream>>>(actA, outb, rowptr, cpair, dinv, b0, N);
    // layer 1: outb -> outb (in-place transform) -> actA
    gemm64_kernel<<<ggrid, THREADS, 0, stream>>>(outb, outb, W1, N);
    agg_kernel  <<<ngrid, THREADS, 0, stream>>>(outb, actA, rowptr, cpair, dinv, b1, N);
    // layer 2: actA -> actA (in-place transform) -> d_out
    gemm64_kernel<<<ggrid, THREADS, 0, stream>>>(actA, actA, W2, N);
    agg_kernel  <<<ngrid, THREADS, 0, stream>>>(actA, outb, rowptr, cpair, dinv, b2, N);
}